// Round 5
// baseline (490.319 us; speedup 1.0000x reference)
//
#include <hip/hip_runtime.h>
#include <hip/hip_bf16.h>

// pooled[s] = sum_k ( S[s,k,:] @ W[k] ) + sum_k count[s,k]*b[k]
// S[s,k,:] = sum of atom rows in segment s with degree k.
//
// V5 pipeline (4 stream ops):
//   memset       : zero cnt (B*K u32, 180 KB)
//   k_fill_wconv : bucket-fill slots[key*CAP+p]=i; K blocks convert
//                  W->bf16^T (half-tile LDS, full occupancy); 8 blocks
//                  zero `out` (needed by phaseB2 atomics)
//   k_phaseA     : one WAVE per BIN PAIR -> up to 8 independent 512B
//                  row-loads in flight (V4 had 4); single combined store
//   k_phaseB2    : MFMA GEMM out += S @ Wb + (cnt . bias), k-split x4
//                  -> 4096 waves (4/SIMD), MFMA chains <= 24, f32 atomics

#define CAP 64   // max atoms per (segment,degree) bin; Poisson(8.7) -> safe

typedef short bf16x8 __attribute__((ext_vector_type(8)));
typedef float f32x4  __attribute__((ext_vector_type(4)));

__device__ __forceinline__ unsigned short f2bf(float f) {
    unsigned int u = __builtin_bit_cast(unsigned int, f);
    u += 0x7fffu + ((u >> 16) & 1u);
    return (unsigned short)(u >> 16);
}

__device__ __forceinline__ int deg_of(int i, const int* __restrict__ ds, int K) {
    int k = 0, end = 0;
    for (int kk = 0; kk < K; ++kk) { end += ds[2 * kk + 1]; k += (i >= end) ? 1 : 0; }
    return k;
}

__device__ __forceinline__ float4 f4add(float4 a, float4 b) {
    return make_float4(a.x + b.x, a.y + b.y, a.z + b.z, a.w + b.w);
}

// blocks [0,nb)        : bucket fill
// blocks [nb,nb+K)     : W[k][f][c] f32 -> Wb[k][c][f] bf16 (two half-tiles,
//                        16.6 KB LDS so fill blocks keep full occupancy)
// blocks [nb+K,nb+K+8) : zero out (B*128 f32) for phaseB2 atomics
__global__ __launch_bounds__(256) void k_fill_wconv(
    const int* __restrict__ mem, const int* __restrict__ ds,
    const float* __restrict__ W,
    unsigned* __restrict__ cnt, unsigned* __restrict__ slots,
    unsigned short* __restrict__ Wb, float* __restrict__ out,
    int N, int K, int nb, int B)
{
    int bx = blockIdx.x;
    if (bx >= nb + K) {                       // ---- out-zero blocks ----
        int zb = bx - nb - K;
        f32x4* o4 = reinterpret_cast<f32x4*>(out);
        int tot = (B * 128) >> 2;
        for (int e = zb * 256 + threadIdx.x; e < tot; e += 8 * 256)
            o4[e] = (f32x4){0.f, 0.f, 0.f, 0.f};
        return;
    }
    if (bx >= nb) {                           // ---- W conversion ----
        __shared__ unsigned short t[64 * 130];   // 16.6 KB
        int k = bx - nb;
        const float* Wk = W + (size_t)k * 16384;
        unsigned short* Wbk = Wb + (size_t)k * 16384;
        #pragma unroll 1
        for (int h = 0; h < 2; ++h) {
            for (int e = threadIdx.x; e < 8192; e += 256) {
                int fl = e >> 7, c = e & 127;        // fl: 0..63
                t[fl * 130 + c] = f2bf(Wk[(size_t)(h * 64 + fl) * 128 + c]);
            }
            __syncthreads();
            for (int e = threadIdx.x; e < 8192; e += 256) {
                int c = e >> 6, fl = e & 63;         // c: 0..127
                Wbk[(size_t)c * 128 + h * 64 + fl] = t[fl * 130 + c];
            }
            __syncthreads();
        }
        return;
    }
    int i = bx * 256 + threadIdx.x;           // ---- bucket fill ----
    if (i >= N) return;
    int key = mem[i] * K + deg_of(i, ds, K);
    unsigned p = atomicAdd(&cnt[key], 1u);
    if (p < CAP) slots[(size_t)key * CAP + p] = (unsigned)i;
}

// One WAVE per BIN PAIR (2p, 2p+1). Lanes: rpar = lane>>5 (row parity),
// f4 = lane&31 (float4 within the 128-float row); each row read = one
// contiguous 512 B. Per batch iteration the wave issues up to 8 independent
// row-loads (4 per bin) -> 2x the memory-level parallelism of V4 with no
// extra redundant loads. Final store: rpar0 lanes write bin A's S row,
// rpar1 lanes write bin B's (one instruction, 512 B total).
__global__ __launch_bounds__(256) void k_phaseA(
    const float* __restrict__ atoms,
    const unsigned* __restrict__ cnt,
    const unsigned* __restrict__ slots,
    unsigned short* __restrict__ S, int KB)
{
    int pair = blockIdx.x * 4 + (threadIdx.x >> 6);
    int binA = pair * 2;
    if (binA >= KB) return;
    int binB = binA + 1;
    bool hasB = (binB < KB);

    int lane = threadIdx.x & 63;
    int rpar = lane >> 5;
    int f4   = lane & 31;

    int nA = (int)cnt[binA];  if (nA > CAP) nA = CAP;
    int nB = hasB ? (int)cnt[binB] : 0;  if (nB > CAP) nB = CAP;
    const unsigned* slA = slots + (size_t)binA * CAP;
    const unsigned* slB = slots + (size_t)binB * CAP;

    const float4 z4 = make_float4(0.f, 0.f, 0.f, 0.f);
    float4 AA0 = z4, AA1 = z4, AA2 = z4, AA3 = z4;
    float4 BB0 = z4, BB1 = z4, BB2 = z4, BB3 = z4;

    int nmax = nA > nB ? nA : nB;
    for (int j = rpar; j < nmax; j += 8) {
        int j1 = j + 2, j2 = j + 4, j3 = j + 6;
        float4 a0 = z4, a1 = z4, a2 = z4, a3 = z4;
        float4 b0 = z4, b1 = z4, b2 = z4, b3 = z4;
        if (j < nA) {                          // wave-uniform branch
            unsigned r0 = slA[j];
            unsigned r1 = slA[j1 < nA ? j1 : j];   // clamped: safe, discarded
            unsigned r2 = slA[j2 < nA ? j2 : j];
            unsigned r3 = slA[j3 < nA ? j3 : j];
            a0 = *reinterpret_cast<const float4*>(atoms + (size_t)r0 * 128 + f4 * 4);
            a1 = *reinterpret_cast<const float4*>(atoms + (size_t)r1 * 128 + f4 * 4);
            a2 = *reinterpret_cast<const float4*>(atoms + (size_t)r2 * 128 + f4 * 4);
            a3 = *reinterpret_cast<const float4*>(atoms + (size_t)r3 * 128 + f4 * 4);
            a1 = (j1 < nA) ? a1 : z4;
            a2 = (j2 < nA) ? a2 : z4;
            a3 = (j3 < nA) ? a3 : z4;
        }
        if (j < nB) {
            unsigned r0 = slB[j];
            unsigned r1 = slB[j1 < nB ? j1 : j];
            unsigned r2 = slB[j2 < nB ? j2 : j];
            unsigned r3 = slB[j3 < nB ? j3 : j];
            b0 = *reinterpret_cast<const float4*>(atoms + (size_t)r0 * 128 + f4 * 4);
            b1 = *reinterpret_cast<const float4*>(atoms + (size_t)r1 * 128 + f4 * 4);
            b2 = *reinterpret_cast<const float4*>(atoms + (size_t)r2 * 128 + f4 * 4);
            b3 = *reinterpret_cast<const float4*>(atoms + (size_t)r3 * 128 + f4 * 4);
            b1 = (j1 < nB) ? b1 : z4;
            b2 = (j2 < nB) ? b2 : z4;
            b3 = (j3 < nB) ? b3 : z4;
        }
        AA0 = f4add(AA0, a0); AA1 = f4add(AA1, a1);
        AA2 = f4add(AA2, a2); AA3 = f4add(AA3, a3);
        BB0 = f4add(BB0, b0); BB1 = f4add(BB1, b1);
        BB2 = f4add(BB2, b2); BB3 = f4add(BB3, b3);
    }
    float4 SA = f4add(f4add(AA0, AA1), f4add(AA2, AA3));
    float4 SB = f4add(f4add(BB0, BB1), f4add(BB2, BB3));
    SA.x += __shfl_xor(SA.x, 32, 64);          // merge row parities (bin A)
    SA.y += __shfl_xor(SA.y, 32, 64);
    SA.z += __shfl_xor(SA.z, 32, 64);
    SA.w += __shfl_xor(SA.w, 32, 64);
    SB.x += __shfl_xor(SB.x, 32, 64);          // merge row parities (bin B)
    SB.y += __shfl_xor(SB.y, 32, 64);
    SB.z += __shfl_xor(SB.z, 32, 64);
    SB.w += __shfl_xor(SB.w, 32, 64);

    float4 Sw = (rpar == 0) ? SA : SB;         // rpar0 -> bin A, rpar1 -> bin B
    int    ob = (rpar == 0) ? binA : binB;
    if (rpar == 0 || hasB) {
        unsigned lo = (unsigned)f2bf(Sw.x) | ((unsigned)f2bf(Sw.y) << 16);
        unsigned hi = (unsigned)f2bf(Sw.z) | ((unsigned)f2bf(Sw.w) << 16);
        *reinterpret_cast<uint2*>(S + (size_t)ob * 128 + f4 * 4) = make_uint2(lo, hi);
    }
}

// One wave per (16 segs x 32 cols x K-quarter). 4096 waves -> 4 waves/SIMD,
// MFMA chains <= 24. Partials accumulated via f32 atomics into the
// pre-zeroed out. Bias (cnt . b) added by the kq==0 quarter only.
__global__ __launch_bounds__(64) void k_phaseB2(
    const unsigned short* __restrict__ S,   // [B][K*128] bf16
    const unsigned short* __restrict__ Wb,  // [K][128][128] bf16 ([k][col][f])
    const unsigned* __restrict__ cnt,       // [B*K]
    const float* __restrict__ bias,         // [K][128]
    float* __restrict__ out,                // [B][128] (pre-zeroed)
    int K)
{
    int bx   = blockIdx.x;
    int s0   = (bx >> 4) * 16;
    int c0   = ((bx >> 2) & 3) * 32;
    int kq   = bx & 3;
    int lane = threadIdx.x;
    int quad = lane >> 4, cb = lane & 15;

    const int kbeg = (K * kq) / 4;
    const int kend = (K * (kq + 1)) / 4;

    const int KD = K * 128;
    f32x4 acc0 = (f32x4){0.f, 0.f, 0.f, 0.f};
    f32x4 acc1 = (f32x4){0.f, 0.f, 0.f, 0.f};

    const unsigned short* Arow = S  + (size_t)(s0 + cb) * KD + quad * 8;
    const unsigned short* B0   = Wb + (size_t)(c0 + cb)      * 128 + quad * 8;
    const unsigned short* B1   = Wb + (size_t)(c0 + 16 + cb) * 128 + quad * 8;

    #pragma unroll 2
    for (int kk = kbeg; kk < kend; ++kk) {
        #pragma unroll
        for (int k0 = 0; k0 < 128; k0 += 32) {
            bf16x8 a  = *reinterpret_cast<const bf16x8*>(Arow + kk * 128 + k0);
            bf16x8 b0 = *reinterpret_cast<const bf16x8*>(B0 + (size_t)kk * 16384 + k0);
            bf16x8 b1 = *reinterpret_cast<const bf16x8*>(B1 + (size_t)kk * 16384 + k0);
            acc0 = __builtin_amdgcn_mfma_f32_16x16x32_bf16(a, b0, acc0, 0, 0, 0);
            acc1 = __builtin_amdgcn_mfma_f32_16x16x32_bf16(a, b1, acc1, 0, 0, 0);
        }
    }
    #pragma unroll
    for (int reg = 0; reg < 4; ++reg) {
        int s = s0 + quad * 4 + reg;
        float b0s = 0.f, b1s = 0.f;
        if (kq == 0) {
            for (int k = 0; k < K; ++k) {
                float c = (float)cnt[(size_t)s * K + k];   // true count (bias exact)
                b0s += c * bias[k * 128 + c0 + cb];
                b1s += c * bias[k * 128 + c0 + 16 + cb];
            }
        }
        __hip_atomic_fetch_add(out + (size_t)s * 128 + c0 + cb, acc0[reg] + b0s,
                               __ATOMIC_RELAXED, __HIP_MEMORY_SCOPE_AGENT);
        __hip_atomic_fetch_add(out + (size_t)s * 128 + c0 + 16 + cb, acc1[reg] + b1s,
                               __ATOMIC_RELAXED, __HIP_MEMORY_SCOPE_AGENT);
    }
}

// ---------------- fallback (fused atomic kernel) if ws too small ----------
#define TM 64
#define LDA 136
#define LDW 136
__global__ __launch_bounds__(256, 2) void degree_affine_pool(
    const float* __restrict__ atoms, const float* __restrict__ W,
    const float* __restrict__ bias, const int* __restrict__ deg_slice,
    const int* __restrict__ membership, float* __restrict__ out, int K)
{
    __shared__ unsigned short Alds[TM * LDA];
    __shared__ unsigned short Wlds[128 * LDW];
    const int bid = blockIdx.x, tid = threadIdx.x;
    int k = -1, tile = 0, acc_t = 0;
    for (int kk = 0; kk < K; ++kk) {
        int c = deg_slice[2 * kk + 1];
        int nt = (c + TM - 1) >> 6;
        if (k < 0 && bid < acc_t + nt) { k = kk; tile = bid - acc_t; }
        acc_t += nt;
    }
    if (k < 0) return;
    const int start = deg_slice[2 * k], cnt = deg_slice[2 * k + 1];
    const int row0 = start + tile * TM;
    const int rows_valid = min(TM, cnt - tile * TM);
    for (int e = tid; e < TM * 32; e += 256) {
        int r = e >> 5, f4 = e & 31;
        float4 v = make_float4(0.f, 0.f, 0.f, 0.f);
        if (r < rows_valid)
            v = *reinterpret_cast<const float4*>(atoms + (size_t)(row0 + r) * 128 + f4 * 4);
        unsigned lo = (unsigned)f2bf(v.x) | ((unsigned)f2bf(v.y) << 16);
        unsigned hi = (unsigned)f2bf(v.z) | ((unsigned)f2bf(v.w) << 16);
        *reinterpret_cast<uint2*>(&Alds[r * LDA + f4 * 4]) = make_uint2(lo, hi);
    }
    const float* Wk = W + (size_t)k * 16384;
    for (int e = tid; e < 8192; e += 256) {
        int c = e & 127, f2 = e >> 7;
        unsigned p = (unsigned)f2bf(Wk[(2 * f2) * 128 + c]) |
                     ((unsigned)f2bf(Wk[(2 * f2 + 1) * 128 + c]) << 16);
        *reinterpret_cast<unsigned*>(&Wlds[c * LDW + 2 * f2]) = p;
    }
    __syncthreads();
    const int wave = tid >> 6, lane = tid & 63, quad = lane >> 4, cb = lane & 15;
    f32x4 acc[8];
    #pragma unroll
    for (int ct = 0; ct < 8; ++ct) acc[ct] = (f32x4){0.f, 0.f, 0.f, 0.f};
    #pragma unroll
    for (int k0 = 0; k0 < 128; k0 += 32) {
        bf16x8 af = *reinterpret_cast<const bf16x8*>(&Alds[(wave * 16 + cb) * LDA + k0 + quad * 8]);
        #pragma unroll
        for (int ct = 0; ct < 8; ++ct) {
            bf16x8 bf = *reinterpret_cast<const bf16x8*>(&Wlds[(ct * 16 + cb) * LDW + k0 + quad * 8]);
            acc[ct] = __builtin_amdgcn_mfma_f32_16x16x32_bf16(af, bf, acc[ct], 0, 0, 0);
        }
    }
    int segs[4]; bool valid[4];
    #pragma unroll
    for (int reg = 0; reg < 4; ++reg) {
        int rl = wave * 16 + quad * 4 + reg;
        valid[reg] = (rl < rows_valid);
        segs[reg] = valid[reg] ? membership[row0 + rl] : 0;
    }
    const float* bk = bias + k * 128;
    #pragma unroll
    for (int ct = 0; ct < 8; ++ct) {
        int col = ct * 16 + cb;
        float bv = bk[col];
        #pragma unroll
        for (int reg = 0; reg < 4; ++reg)
            if (valid[reg])
                __hip_atomic_fetch_add(out + (size_t)segs[reg] * 128 + col,
                                       acc[ct][reg] + bv, __ATOMIC_RELAXED,
                                       __HIP_MEMORY_SCOPE_AGENT);
    }
}
// ---------------------------------------------------------------------------

static inline size_t aln(size_t x) { return (x + 255) & ~(size_t)255; }

extern "C" void kernel_launch(void* const* d_in, const int* in_sizes, int n_in,
                              void* d_out, int out_size, void* d_ws, size_t ws_size,
                              hipStream_t stream) {
    const float* atoms = (const float*)d_in[0];
    const float* W     = (const float*)d_in[1];
    const float* bias  = (const float*)d_in[2];
    const int*   deg   = (const int*)d_in[3];
    const int*   mem   = (const int*)d_in[4];
    float*       out   = (float*)d_out;

    const int K  = in_sizes[3] / 2;      // 11
    const int N  = in_sizes[0] / 128;    // 393216
    const int B  = out_size / 128;       // 4096
    const int KB = B * K;                // 45056 bins

    // workspace plan (~23.6 MB)
    size_t oWb   = 0;                       size_t sWb   = (size_t)K * 16384 * 2;
    size_t oCnt  = aln(oWb + sWb);          size_t sCnt  = (size_t)KB * 4;
    size_t oSlot = aln(oCnt + sCnt);        size_t sSlot = (size_t)KB * CAP * 4;
    size_t oS    = aln(oSlot + sSlot);      size_t sS    = (size_t)KB * 128 * 2;
    size_t total = oS + sS;

    if (ws_size < total || (B & 15) != 0) {
        (void)hipMemsetAsync(d_out, 0, (size_t)out_size * sizeof(float), stream);
        const int blocks = (N + TM - 1) / TM + K;
        degree_affine_pool<<<blocks, 256, 0, stream>>>(atoms, W, bias, deg, mem, out, K);
        return;
    }

    char* ws = (char*)d_ws;
    unsigned short* Wb    = (unsigned short*)(ws + oWb);
    unsigned*       cnt   = (unsigned*)(ws + oCnt);
    unsigned*       slots = (unsigned*)(ws + oSlot);
    unsigned short* S     = (unsigned short*)(ws + oS);

    (void)hipMemsetAsync(cnt, 0, sCnt, stream);

    const int nb = (N + 255) / 256;
    const int npair = (KB + 1) / 2;
    k_fill_wconv<<<nb + K + 8, 256, 0, stream>>>(mem, deg, W, cnt, slots, Wb, out, N, K, nb, B);
    k_phaseA    <<<(npair + 3) / 4, 256, 0, stream>>>(atoms, cnt, slots, S, KB);
    k_phaseB2   <<<(B / 16) * 16, 64, 0, stream>>>(S, Wb, cnt, bias, out, K);
}

// Round 7
// 346.179 us; speedup vs baseline: 1.4164x; 1.4164x over previous
//
#include <hip/hip_runtime.h>
#include <hip/hip_bf16.h>

// pooled[s] = sum_k ( S[s,k,:] @ W[k] ) + sum_k count[s,k]*b[k]
// S[s,k,:] = sum of atom rows in segment s with degree k.
//
// V6 (resubmit; round-6 bench was an infra failure, no data) =
// round-0 best (347us) + ONE change: phaseA's serial tail
// (1 load-wait per row) replaced by a single exec-masked batch
// (3 loads in flight, no duplicate HBM traffic).
//   memset       : zero cnt (B*K u32, 180 KB)
//   k_fill_wconv : bucket-fill slots[key*CAP+p]=i (one pass, no sort);
//                  last K blocks convert W -> bf16 transposed
//   k_phaseA     : one WAVE per (s,k) bin: gather rows float4-wide, sum,
//                  cross-parity shfl reduce -> S bf16
//   k_phaseB     : MFMA GEMM out = S @ Wb + (cnt . bias), plain stores
//
// Accounting (rounds 0/2/4/5): dur_us carries ~238us of harness poison
// fills; our pipeline is ~110us of which phaseA ~90. V4 (clamp+discard
// batch, +28us: redundant loads) and V5 (bin-pair, 2x: TLP halved)
// both regressed phaseA -- reverted.

#define CAP 64   // max atoms per (segment,degree) bin; Poisson(8.7) -> safe

typedef short bf16x8 __attribute__((ext_vector_type(8)));
typedef float f32x4  __attribute__((ext_vector_type(4)));

__device__ __forceinline__ unsigned short f2bf(float f) {
    unsigned int u = __builtin_bit_cast(unsigned int, f);
    u += 0x7fffu + ((u >> 16) & 1u);
    return (unsigned short)(u >> 16);
}

__device__ __forceinline__ int deg_of(int i, const int* __restrict__ ds, int K) {
    int k = 0, end = 0;
    for (int kk = 0; kk < K; ++kk) { end += ds[2 * kk + 1]; k += (i >= end) ? 1 : 0; }
    return k;
}

// blocks [0,nb): bucket fill.  blocks [nb,nb+K): W[k][f][c] f32 -> Wb[k][c][f] bf16.
__global__ __launch_bounds__(256) void k_fill_wconv(
    const int* __restrict__ mem, const int* __restrict__ ds,
    const float* __restrict__ W,
    unsigned* __restrict__ cnt, unsigned* __restrict__ slots,
    unsigned short* __restrict__ Wb, int N, int K, int nb)
{
    int bx = blockIdx.x;
    if (bx >= nb) {
        __shared__ unsigned short t[128 * 130];
        int k = bx - nb;
        const float* Wk = W + (size_t)k * 16384;
        unsigned short* Wbk = Wb + (size_t)k * 16384;
        for (int e = threadIdx.x; e < 16384; e += 256) {
            int f = e >> 7, c = e & 127;
            t[f * 130 + c] = f2bf(Wk[e]);
        }
        __syncthreads();
        for (int e = threadIdx.x; e < 16384; e += 256) {
            int c = e >> 7, f = e & 127;
            Wbk[e] = t[f * 130 + c];
        }
        return;
    }
    int i = bx * 256 + threadIdx.x;
    if (i >= N) return;
    int key = mem[i] * K + deg_of(i, ds, K);
    unsigned p = atomicAdd(&cnt[key], 1u);
    if (p < CAP) slots[(size_t)key * CAP + p] = (unsigned)i;
}

__device__ __forceinline__ float4 f4add(float4 a, float4 b) {
    return make_float4(a.x + b.x, a.y + b.y, a.z + b.z, a.w + b.w);
}

// One WAVE per bin. Lanes: rpar = lane>>5 (row parity), f4 = lane&31
// (float4 within the 128-float row). Each row read = one contiguous 512 B.
__global__ __launch_bounds__(256) void k_phaseA(
    const float* __restrict__ atoms,
    const unsigned* __restrict__ cnt,
    const unsigned* __restrict__ slots,
    unsigned short* __restrict__ S, int KB)
{
    int bin = blockIdx.x * 4 + (threadIdx.x >> 6);
    if (bin >= KB) return;
    int lane = threadIdx.x & 63;
    int rpar = lane >> 5;
    int f4   = lane & 31;
    int n = (int)cnt[bin];
    if (n > CAP) n = CAP;
    const unsigned* sl = slots + (size_t)bin * CAP;

    const float4 z4 = make_float4(0.f, 0.f, 0.f, 0.f);
    float4 A0 = z4, A1 = z4, A2 = z4, A3 = z4;
    int j = rpar;
    for (; j + 6 < n; j += 8) {                 // 8 rows in flight per wave
        unsigned r0 = sl[j], r1 = sl[j + 2], r2 = sl[j + 4], r3 = sl[j + 6];
        float4 v0 = *reinterpret_cast<const float4*>(atoms + (size_t)r0 * 128 + f4 * 4);
        float4 v1 = *reinterpret_cast<const float4*>(atoms + (size_t)r1 * 128 + f4 * 4);
        float4 v2 = *reinterpret_cast<const float4*>(atoms + (size_t)r2 * 128 + f4 * 4);
        float4 v3 = *reinterpret_cast<const float4*>(atoms + (size_t)r3 * 128 + f4 * 4);
        A0 = f4add(A0, v0); A1 = f4add(A1, v1);
        A2 = f4add(A2, v2); A3 = f4add(A3, v3);
    }
    // Exec-masked tail batch: at most rows j, j+2, j+4 remain per parity
    // (j+6 < n handled by main loop). Slot indices clamped (in-bounds, dup
    // slot read = cache hit); row loads predicated per-lane so masked-off
    // lanes fetch NOTHING (V4's clamp+discard duplicated HBM traffic).
    // Adds deferred after all loads -> 3 loads under one waitcnt.
    if (j < n) {
        unsigned r0 = sl[j];
        unsigned r1 = sl[(j + 2 < n) ? j + 2 : j];
        unsigned r2 = sl[(j + 4 < n) ? j + 4 : j];
        float4 v0 = z4, v1 = z4, v2 = z4;
        v0 = *reinterpret_cast<const float4*>(atoms + (size_t)r0 * 128 + f4 * 4);
        if (j + 2 < n)
            v1 = *reinterpret_cast<const float4*>(atoms + (size_t)r1 * 128 + f4 * 4);
        if (j + 4 < n)
            v2 = *reinterpret_cast<const float4*>(atoms + (size_t)r2 * 128 + f4 * 4);
        A0 = f4add(A0, v0); A1 = f4add(A1, v1); A2 = f4add(A2, v2);
    }
    float4 Sm = f4add(f4add(A0, A1), f4add(A2, A3));
    Sm.x += __shfl_xor(Sm.x, 32, 64);           // merge row parities
    Sm.y += __shfl_xor(Sm.y, 32, 64);
    Sm.z += __shfl_xor(Sm.z, 32, 64);
    Sm.w += __shfl_xor(Sm.w, 32, 64);
    if (rpar == 0) {
        unsigned lo = (unsigned)f2bf(Sm.x) | ((unsigned)f2bf(Sm.y) << 16);
        unsigned hi = (unsigned)f2bf(Sm.z) | ((unsigned)f2bf(Sm.w) << 16);
        *reinterpret_cast<uint2*>(S + (size_t)bin * 128 + f4 * 4) = make_uint2(lo, hi);
    }
}

// One wave per (16 segments x 32 cols); K-chain = K*128. Bias from cnt.
__global__ __launch_bounds__(64) void k_phaseB(
    const unsigned short* __restrict__ S,   // [B][K*128] bf16
    const unsigned short* __restrict__ Wb,  // [K][128][128] bf16 ([k][col][f])
    const unsigned* __restrict__ cnt,       // [B*K]
    const float* __restrict__ bias,         // [K][128]
    float* __restrict__ out,                // [B][128]
    int K)
{
    int bx   = blockIdx.x;
    int s0   = (bx >> 2) * 16;
    int c0   = (bx & 3) * 32;
    int lane = threadIdx.x;
    int quad = lane >> 4, cb = lane & 15;

    const int KD = K * 128;
    f32x4 acc0 = (f32x4){0.f, 0.f, 0.f, 0.f};
    f32x4 acc1 = (f32x4){0.f, 0.f, 0.f, 0.f};

    const unsigned short* Arow = S  + (size_t)(s0 + cb) * KD + quad * 8;
    const unsigned short* B0   = Wb + (size_t)(c0 + cb)      * 128 + quad * 8;
    const unsigned short* B1   = Wb + (size_t)(c0 + 16 + cb) * 128 + quad * 8;

    #pragma unroll 1
    for (int kk = 0; kk < K; ++kk) {
        #pragma unroll
        for (int k0 = 0; k0 < 128; k0 += 32) {
            bf16x8 a  = *reinterpret_cast<const bf16x8*>(Arow + kk * 128 + k0);
            bf16x8 b0 = *reinterpret_cast<const bf16x8*>(B0 + (size_t)kk * 16384 + k0);
            bf16x8 b1 = *reinterpret_cast<const bf16x8*>(B1 + (size_t)kk * 16384 + k0);
            acc0 = __builtin_amdgcn_mfma_f32_16x16x32_bf16(a, b0, acc0, 0, 0, 0);
            acc1 = __builtin_amdgcn_mfma_f32_16x16x32_bf16(a, b1, acc1, 0, 0, 0);
        }
    }
    #pragma unroll
    for (int reg = 0; reg < 4; ++reg) {
        int s = s0 + quad * 4 + reg;
        float b0s = 0.f, b1s = 0.f;
        for (int k = 0; k < K; ++k) {
            float c = (float)cnt[(size_t)s * K + k];   // true count (bias exact)
            b0s += c * bias[k * 128 + c0 + cb];
            b1s += c * bias[k * 128 + c0 + 16 + cb];
        }
        out[(size_t)s * 128 + c0 + cb]      = acc0[reg] + b0s;
        out[(size_t)s * 128 + c0 + 16 + cb] = acc1[reg] + b1s;
    }
}

// ---------------- fallback (fused atomic kernel) if ws too small ----------
#define TM 64
#define LDA 136
#define LDW 136
__global__ __launch_bounds__(256, 2) void degree_affine_pool(
    const float* __restrict__ atoms, const float* __restrict__ W,
    const float* __restrict__ bias, const int* __restrict__ deg_slice,
    const int* __restrict__ membership, float* __restrict__ out, int K)
{
    __shared__ unsigned short Alds[TM * LDA];
    __shared__ unsigned short Wlds[128 * LDW];
    const int bid = blockIdx.x, tid = threadIdx.x;
    int k = -1, tile = 0, acc_t = 0;
    for (int kk = 0; kk < K; ++kk) {
        int c = deg_slice[2 * kk + 1];
        int nt = (c + TM - 1) >> 6;
        if (k < 0 && bid < acc_t + nt) { k = kk; tile = bid - acc_t; }
        acc_t += nt;
    }
    if (k < 0) return;
    const int start = deg_slice[2 * k], cnt = deg_slice[2 * k + 1];
    const int row0 = start + tile * TM;
    const int rows_valid = min(TM, cnt - tile * TM);
    for (int e = tid; e < TM * 32; e += 256) {
        int r = e >> 5, f4 = e & 31;
        float4 v = make_float4(0.f, 0.f, 0.f, 0.f);
        if (r < rows_valid)
            v = *reinterpret_cast<const float4*>(atoms + (size_t)(row0 + r) * 128 + f4 * 4);
        unsigned lo = (unsigned)f2bf(v.x) | ((unsigned)f2bf(v.y) << 16);
        unsigned hi = (unsigned)f2bf(v.z) | ((unsigned)f2bf(v.w) << 16);
        *reinterpret_cast<uint2*>(&Alds[r * LDA + f4 * 4]) = make_uint2(lo, hi);
    }
    const float* Wk = W + (size_t)k * 16384;
    for (int e = tid; e < 8192; e += 256) {
        int c = e & 127, f2 = e >> 7;
        unsigned p = (unsigned)f2bf(Wk[(2 * f2) * 128 + c]) |
                     ((unsigned)f2bf(Wk[(2 * f2 + 1) * 128 + c]) << 16);
        *reinterpret_cast<unsigned*>(&Wlds[c * LDW + 2 * f2]) = p;
    }
    __syncthreads();
    const int wave = tid >> 6, lane = tid & 63, quad = lane >> 4, cb = lane & 15;
    f32x4 acc[8];
    #pragma unroll
    for (int ct = 0; ct < 8; ++ct) acc[ct] = (f32x4){0.f, 0.f, 0.f, 0.f};
    #pragma unroll
    for (int k0 = 0; k0 < 128; k0 += 32) {
        bf16x8 af = *reinterpret_cast<const bf16x8*>(&Alds[(wave * 16 + cb) * LDA + k0 + quad * 8]);
        #pragma unroll
        for (int ct = 0; ct < 8; ++ct) {
            bf16x8 bf = *reinterpret_cast<const bf16x8*>(&Wlds[(ct * 16 + cb) * LDW + k0 + quad * 8]);
            acc[ct] = __builtin_amdgcn_mfma_f32_16x16x32_bf16(af, bf, acc[ct], 0, 0, 0);
        }
    }
    int segs[4]; bool valid[4];
    #pragma unroll
    for (int reg = 0; reg < 4; ++reg) {
        int rl = wave * 16 + quad * 4 + reg;
        valid[reg] = (rl < rows_valid);
        segs[reg] = valid[reg] ? membership[row0 + rl] : 0;
    }
    const float* bk = bias + k * 128;
    #pragma unroll
    for (int ct = 0; ct < 8; ++ct) {
        int col = ct * 16 + cb;
        float bv = bk[col];
        #pragma unroll
        for (int reg = 0; reg < 4; ++reg)
            if (valid[reg])
                __hip_atomic_fetch_add(out + (size_t)segs[reg] * 128 + col,
                                       acc[ct][reg] + bv, __ATOMIC_RELAXED,
                                       __HIP_MEMORY_SCOPE_AGENT);
    }
}
// ---------------------------------------------------------------------------

static inline size_t aln(size_t x) { return (x + 255) & ~(size_t)255; }

extern "C" void kernel_launch(void* const* d_in, const int* in_sizes, int n_in,
                              void* d_out, int out_size, void* d_ws, size_t ws_size,
                              hipStream_t stream) {
    const float* atoms = (const float*)d_in[0];
    const float* W     = (const float*)d_in[1];
    const float* bias  = (const float*)d_in[2];
    const int*   deg   = (const int*)d_in[3];
    const int*   mem   = (const int*)d_in[4];
    float*       out   = (float*)d_out;

    const int K  = in_sizes[3] / 2;      // 11
    const int N  = in_sizes[0] / 128;    // 393216
    const int B  = out_size / 128;       // 4096
    const int KB = B * K;                // 45056 bins

    // workspace plan (~23.6 MB)
    size_t oWb   = 0;                       size_t sWb   = (size_t)K * 16384 * 2;
    size_t oCnt  = aln(oWb + sWb);          size_t sCnt  = (size_t)KB * 4;
    size_t oSlot = aln(oCnt + sCnt);        size_t sSlot = (size_t)KB * CAP * 4;
    size_t oS    = aln(oSlot + sSlot);      size_t sS    = (size_t)KB * 128 * 2;
    size_t total = oS + sS;

    if (ws_size < total || (B & 15) != 0) {
        (void)hipMemsetAsync(d_out, 0, (size_t)out_size * sizeof(float), stream);
        const int blocks = (N + TM - 1) / TM + K;
        degree_affine_pool<<<blocks, 256, 0, stream>>>(atoms, W, bias, deg, mem, out, K);
        return;
    }

    char* ws = (char*)d_ws;
    unsigned short* Wb    = (unsigned short*)(ws + oWb);
    unsigned*       cnt   = (unsigned*)(ws + oCnt);
    unsigned*       slots = (unsigned*)(ws + oSlot);
    unsigned short* S     = (unsigned short*)(ws + oS);

    (void)hipMemsetAsync(cnt, 0, sCnt, stream);

    const int nb = (N + 255) / 256;
    k_fill_wconv<<<nb + K, 256, 0, stream>>>(mem, deg, W, cnt, slots, Wb, N, K, nb);
    k_phaseA    <<<(KB + 3) / 4, 256, 0, stream>>>(atoms, cnt, slots, S, KB);
    k_phaseB    <<<(B / 16) * 4, 64, 0, stream>>>(S, Wb, cnt, bias, out, K);
}